// Round 30
// baseline (187.424 us; speedup 1.0000x reference)
//
#include <hip/hip_runtime.h>

typedef _Float16 f16;
typedef _Float16 f16x8 __attribute__((ext_vector_type(8)));
typedef _Float16 f16x4 __attribute__((ext_vector_type(4)));
typedef float f32x4 __attribute__((ext_vector_type(4)));
typedef float fl4 __attribute__((ext_vector_type(4)));

#define NEG_INF_F (-1e10f)

__device__ __forceinline__ void stage16(const f16* g, f16* l) {
    __builtin_amdgcn_global_load_lds((const __attribute__((address_space(1))) void*)g,
                                     (__attribute__((address_space(3))) void*)l, 16, 0, 0);
}

// ---------------- prep2: tiled transposes + conversions (unchanged) -------
__global__ __launch_bounds__(256) void prep2(const float* __restrict__ me,
                                             const float* __restrict__ mw1,
                                             const float* __restrict__ vw1,
                                             const float* __restrict__ mw2,
                                             const float* __restrict__ vw2,
                                             const float* __restrict__ aw1,
                                             const float* __restrict__ cl,
                                             f16* __restrict__ me_h,
                                             f16* __restrict__ mw1t, f16* __restrict__ vw1t,
                                             f16* __restrict__ mw2t, f16* __restrict__ vw2t,
                                             f16* __restrict__ aw1t, f16* __restrict__ cl_h) {
    int bx = blockIdx.x, t = threadIdx.x;
    if (bx < 1792) {
        __shared__ float tile[32][33];
        const float* src; f16* dst; int Ksrc, Kp, tid;
        if (bx < 512)       { src = mw1; dst = mw1t; Ksrc = 1024; Kp = 1024; tid = bx; }
        else if (bx < 1024) { src = vw1; dst = vw1t; Ksrc = 1000; Kp = 1024; tid = bx - 512; }
        else if (bx < 1280) { src = mw2; dst = mw2t; Ksrc = 512;  Kp = 512;  tid = bx - 1024; }
        else if (bx < 1536) { src = vw2; dst = vw2t; Ksrc = 512;  Kp = 512;  tid = bx - 1280; }
        else                { src = aw1; dst = aw1t; Ksrc = 512;  Kp = 512;  tid = bx - 1536; }
        int tk = tid >> 4, tn = tid & 15;
        int x = t & 31, y = t >> 5;
        #pragma unroll
        for (int r = 0; r < 4; r++) {
            int k = tk * 32 + y * 4 + r;
            tile[y * 4 + r][x] = (k < Ksrc) ? src[k * 512 + tn * 32 + x] : 0.f;
        }
        __syncthreads();
        #pragma unroll
        for (int r = 0; r < 4; r++) {
            int n = tn * 32 + y * 4 + r;
            dst[n * Kp + tk * 32 + x] = (f16)tile[x][y * 4 + r];
        }
        return;
    }
    if (bx < 3840) {
        int i = (bx - 1792) * 256 + t;
        fl4 v = *(const fl4*)(me + i * 4);
        f16x4 h;
        #pragma unroll
        for (int e = 0; e < 4; e++) h[e] = (f16)v[e];
        *(f16x4*)(me_h + i * 4) = h;
        return;
    }
    {
        int i = (bx - 3840) * 256 + t;
        int idx = i * 4;
        int r = idx >> 10, k0 = idx & 1023;
        f16x4 h;
        if (k0 < 1000) {
            fl4 v = *(const fl4*)(cl + r * 1000 + k0);
            #pragma unroll
            for (int e = 0; e < 4; e++) h[e] = (f16)v[e];
        } else {
            #pragma unroll
            for (int e = 0; e < 4; e++) h[e] = (f16)0.f;
        }
        *(f16x4*)(cl_h + idx) = h;
    }
}

// ---------------- staged GEMM, 64x64 tile, 4-buffer paired barriers (R17 version) ----
__global__ __launch_bounds__(256, 4) void gemm_stg3(const f16* __restrict__ Am,
                                                    const f16* __restrict__ Av,
                                                    const f16* __restrict__ Wm,
                                                    const f16* __restrict__ Wv,
                                                    const float* __restrict__ bm,
                                                    const float* __restrict__ bv,
                                                    f16* __restrict__ om,
                                                    f16* __restrict__ ov,
                                                    int K, int relu) {
    __shared__ f16 ab[4][2048], bb[4][2048];  // 32KB

    int t = threadIdx.x, lane = t & 63, w = t >> 6;
    int rl = lane & 15, kg = lane >> 4;
    int mq = w & 1, nq = w >> 1;
    bool isv = blockIdx.x >= 32;
    int mb = isv ? blockIdx.x - 32 : blockIdx.x;
    const f16* A = isv ? Av : Am;
    const f16* Wt = isv ? Wv : Wm;
    const float* bias = isv ? bv : bm;
    f16* out = isv ? ov : om;
    int m0 = mb * 64, n0 = blockIdx.y * 64;
    int pu = kg ^ ((rl >> 1) & 3);

    int srow = t >> 2;
    int sk8 = (t & 3) ^ ((srow >> 1) & 3);
    const f16* a_src = A + (m0 + srow) * K + sk8 * 8;
    const f16* b_src = Wt + (n0 + srow) * K + sk8 * 8;
    int ndbl = K >> 6;   // double-steps (K/64)

    f32x4 acc[2][2] = {};

    stage16(a_src, &ab[0][t * 8]);
    stage16(b_src, &bb[0][t * 8]);
    stage16(a_src + 32, &ab[1][t * 8]);
    stage16(b_src + 32, &bb[1][t * 8]);
    __syncthreads();

    for (int ss = 0; ss < ndbl; ss++) {
        if (ss + 1 < ndbl) {
            int ka = (ss * 2 + 2) * 32, kb = (ss * 2 + 3) * 32;
            stage16(a_src + ka, &ab[(ss * 2 + 2) & 3][t * 8]);
            stage16(b_src + ka, &bb[(ss * 2 + 2) & 3][t * 8]);
            stage16(a_src + kb, &ab[(ss * 2 + 3) & 3][t * 8]);
            stage16(b_src + kb, &bb[(ss * 2 + 3) & 3][t * 8]);
        }
        #pragma unroll
        for (int h = 0; h < 2; h++) {
            int cur = (ss * 2 + h) & 3;
            f16x8 af[2], bf[2];
            #pragma unroll
            for (int f = 0; f < 2; f++) {
                af[f] = *(const f16x8*)&ab[cur][((mq * 32 + f * 16 + rl) * 4 + pu) * 8];
                bf[f] = *(const f16x8*)&bb[cur][((nq * 32 + f * 16 + rl) * 4 + pu) * 8];
            }
            #pragma unroll
            for (int fi = 0; fi < 2; fi++)
                #pragma unroll
                for (int fj = 0; fj < 2; fj++)
                    acc[fi][fj] = __builtin_amdgcn_mfma_f32_16x16x32_f16(af[fi], bf[fj], acc[fi][fj], 0, 0, 0);
        }
        __syncthreads();
    }

    #pragma unroll
    for (int fi = 0; fi < 2; fi++)
        #pragma unroll
        for (int fj = 0; fj < 2; fj++) {
            int col = n0 + nq * 32 + fj * 16 + rl;
            float bv2 = bias[col];
            #pragma unroll
            for (int r = 0; r < 4; r++) {
                int row = m0 + mq * 32 + fi * 16 + kg * 4 + r;
                float v = acc[fi][fj][r] + bv2;
                if (relu) v = fmaxf(v, 0.f);
                out[row * 512 + col] = (f16)v;
            }
        }
}

// ---------------- fused attention f18: f14 exactly, bounds(256,3) (3 blocks/CU) -----
// Single-variable A/B vs R17: residency cap 2 -> 3 blocks/CU (12 waves/CU, grid 1152
// = 1.5 rounds). VGPR 116 < 170 cap, LDS 42KB x 3 = 126KB < 160KB. Everything else
// identical: acc[c4][fi2][fj4], 10 reads/32 MFMAs, 3-buffer counted-vmcnt schedule.
__global__ __launch_bounds__(256, 3) void attn_f18(const f16* __restrict__ men,
                                                   const f16* __restrict__ vis,
                                                   const f16* __restrict__ aw1t,
                                                   const float* __restrict__ ab1,
                                                   const float* __restrict__ aw2,
                                                   float* __restrict__ partial) {
    __shared__ f16 awb[3][4096];    // [buf][row j 0..127][unit 0..3][8 f16], swizzled
    __shared__ f16 mnb[3][2048];    // [buf][row m 0..63][unit][8], swizzled
    __shared__ f16 vist[2048];      // [c 0..3][k 0..511], staged once
    __shared__ float red[2][4][64]; // [jq][c][m]

    int t = threadIdx.x, lane = t & 63, w = t >> 6;
    int mh = w & 1, jq = w >> 1;
    int cq = blockIdx.x, jh = blockIdx.y, b = blockIdx.z;
    int c0 = cq * 4;
    int rl = lane & 15, kg = lane >> 4;
    int pu = kg ^ ((rl >> 1) & 3);

    int srow = t >> 2;                       // 0..63
    int sk8 = (t & 3) ^ ((srow >> 1) & 3);
    const f16* aw_src = aw1t + (jh * 128 + srow) * 512 + sk8 * 8;   // + i*64*512
    const f16* mn_src = men + (b * 64 + srow) * 512 + sk8 * 8;
    const f16* vi_src = vis + (b * 36 + c0 + (t >> 6)) * 512 + (t & 63) * 8;

    f32x4 acc[4][2][4] = {};   // [c][fi][fj]

    // prologue: vist + batches 0,1 (each batch: 2 aw + 1 mn per thread)
    stage16(vi_src, &vist[t * 8]);
    stage16(aw_src, &awb[0][t * 8]);
    stage16(aw_src + 64 * 512, &awb[0][2048 + t * 8]);
    stage16(mn_src, &mnb[0][t * 8]);
    stage16(aw_src + 32, &awb[1][t * 8]);
    stage16(aw_src + 64 * 512 + 32, &awb[1][2048 + t * 8]);
    stage16(mn_src + 32, &mnb[1][t * 8]);
    asm volatile("s_waitcnt vmcnt(3)" ::: "memory");   // retire vist + batch0
    __builtin_amdgcn_s_barrier();
    __builtin_amdgcn_sched_barrier(0);

    #pragma unroll
    for (int s = 0; s < 16; s++) {
        if (s > 0) {
            if (s == 15) asm volatile("s_waitcnt vmcnt(0)" ::: "memory");
            else         asm volatile("s_waitcnt vmcnt(3)" ::: "memory");
            __builtin_amdgcn_s_barrier();
            __builtin_amdgcn_sched_barrier(0);
        }
        if (s <= 13) {  // issue batch s+2 EARLY (lands during steps s, s+1)
            int k2 = (s + 2) * 32;
            int nb = (s + 2) % 3;
            stage16(aw_src + k2, &awb[nb][t * 8]);
            stage16(aw_src + 64 * 512 + k2, &awb[nb][2048 + t * 8]);
            stage16(mn_src + k2, &mnb[nb][t * 8]);
        }

        const int cur = s % 3;
        f16x8 mm[2], bf[4], vv[4];
        #pragma unroll
        for (int fi = 0; fi < 2; fi++)
            mm[fi] = *(const f16x8*)&mnb[cur][((mh * 32 + fi * 16 + rl) * 4 + pu) * 8];
        #pragma unroll
        for (int fj = 0; fj < 4; fj++)
            bf[fj] = *(const f16x8*)&awb[cur][((jq * 64 + fj * 16 + rl) * 4 + pu) * 8];
        #pragma unroll
        for (int c = 0; c < 4; c++)
            vv[c] = *(const f16x8*)&vist[c * 512 + s * 32 + kg * 8];  // broadcast

        #pragma unroll
        for (int fi = 0; fi < 2; fi++)
            #pragma unroll
            for (int c = 0; c < 4; c++) {
                f16x8 a = mm[fi] * vv[c];   // 4 pk_mul -> feeds 4 MFMAs
                #pragma unroll
                for (int fj = 0; fj < 4; fj++)
                    acc[c][fi][fj] = __builtin_amdgcn_mfma_f32_16x16x32_f16(a, bf[fj], acc[c][fi][fj], 0, 0, 0);
            }
    }

    // fold: part[m] = sum over this wave's 64 j of relu(acc + ab1) * aw2 (fp32)
    int j0 = jh * 128 + jq * 64;
    float ab1v[4], aw2v[4];
    #pragma unroll
    for (int fj = 0; fj < 4; fj++) {
        int j = j0 + fj * 16 + rl;
        ab1v[fj] = ab1[j];
        aw2v[fj] = aw2[j];
    }
    #pragma unroll
    for (int c = 0; c < 4; c++) {
        float part[2][4];
        #pragma unroll
        for (int fi = 0; fi < 2; fi++)
            #pragma unroll
            for (int r = 0; r < 4; r++) {
                float sv = 0.f;
                #pragma unroll
                for (int fj = 0; fj < 4; fj++)
                    sv += fmaxf(acc[c][fi][fj][r] + ab1v[fj], 0.f) * aw2v[fj];
                part[fi][r] = sv;
            }
        #pragma unroll
        for (int mask = 1; mask < 16; mask <<= 1)
            #pragma unroll
            for (int fi = 0; fi < 2; fi++)
                #pragma unroll
                for (int r = 0; r < 4; r++)
                    part[fi][r] += __shfl_xor(part[fi][r], mask);
        float myv = 0.f;
        #pragma unroll
        for (int fi = 0; fi < 2; fi++)
            #pragma unroll
            for (int r = 0; r < 4; r++)
                myv = (rl == fi * 4 + r) ? part[fi][r] : myv;
        if (rl < 8) {
            int m = mh * 32 + (rl >> 2) * 16 + kg * 4 + (rl & 3);
            red[jq][c][m] = myv;
        }
    }
    __syncthreads();

    if (t < 256) {
        int ci = t >> 6, m = t & 63;
        float s = red[0][ci][m] + red[1][ci][m];
        partial[((jh * 32 + b) * 64 + m) * 36 + c0 + ci] = s;
    }
}

// ---------------- post-process: sum 4 jh partials, + ab2, masks, NEG_INF ------------
__global__ __launch_bounds__(256) void postproc(const float* __restrict__ partial,
                                                const float* __restrict__ mm,
                                                const float* __restrict__ cm,
                                                const float* __restrict__ ab2,
                                                float* __restrict__ out) {
    int i = blockIdx.x * 256 + threadIdx.x;  // < 73728
    int b = i / 2304;
    int rest = i - b * 2304;
    int m = rest / 36, c = rest - m * 36;
    float s = 0.f;
    #pragma unroll
    for (int jh = 0; jh < 4; jh++)
        s += partial[((jh * 32 + b) * 64 + m) * 36 + c];
    float v = (s + ab2[0]) * mm[b * 64 + m] * cm[b * 36 + c];
    out[i] = (v != 0.f) ? v : NEG_INF_F;
}

extern "C" void kernel_launch(void* const* d_in, const int* in_sizes, int n_in,
                              void* d_out, int out_size, void* d_ws, size_t ws_size,
                              hipStream_t stream) {
    const float* ME  = (const float*)d_in[0];   // (32,64,1024)
    const float* CL  = (const float*)d_in[1];   // (32,36,1000)
    const float* MM  = (const float*)d_in[2];   // (32,64)
    const float* CM  = (const float*)d_in[3];   // (32,36)
    const float* VW1 = (const float*)d_in[4];   // (1000,512)
    const float* VB1 = (const float*)d_in[5];
    const float* VW2 = (const float*)d_in[6];   // (512,512)
    const float* VB2 = (const float*)d_in[7];
    const float* MW1 = (const float*)d_in[8];   // (1024,512)
    const float* MB1 = (const float*)d_in[9];
    const float* MW2 = (const float*)d_in[10];  // (512,512)
    const float* MB2 = (const float*)d_in[11];
    const float* AW1 = (const float*)d_in[12];  // (512,512)
    const float* AB1 = (const float*)d_in[13];
    const float* AW2 = (const float*)d_in[14];  // (512,1)
    const float* AB2 = (const float*)d_in[15];  // (1,)
    float* out = (float*)d_out;

    char* ws = (char*)d_ws;
    f16* me_h  = (f16*)ws; ws += (size_t)2048 * 1024 * 2;
    f16* cl_h  = (f16*)ws; ws += (size_t)1152 * 1024 * 2;
    f16* mw1t  = (f16*)ws; ws += (size_t)512 * 1024 * 2;
    f16* vw1t  = (f16*)ws; ws += (size_t)512 * 1024 * 2;
    f16* mw2t  = (f16*)ws; ws += (size_t)512 * 512 * 2;
    f16* vw2t  = (f16*)ws; ws += (size_t)512 * 512 * 2;
    f16* aw1t  = (f16*)ws; ws += (size_t)512 * 512 * 2;
    f16* men1  = (f16*)ws; ws += (size_t)2048 * 512 * 2;
    f16* menh  = (f16*)ws; ws += (size_t)2048 * 512 * 2;
    f16* vis1  = (f16*)ws; ws += (size_t)1152 * 512 * 2;
    f16* vish  = (f16*)ws; ws += (size_t)1152 * 512 * 2;
    float* part = (float*)ws; ws += (size_t)4 * 32 * 64 * 36 * 4;

    prep2<<<4992, 256, 0, stream>>>(ME, MW1, VW1, MW2, VW2, AW1, CL,
                                    me_h, mw1t, vw1t, mw2t, vw2t, aw1t, cl_h);
    gemm_stg3<<<dim3(50, 8), 256, 0, stream>>>(me_h, cl_h, mw1t, vw1t, MB1, VB1,
                                               men1, vis1, 1024, 1);
    gemm_stg3<<<dim3(50, 8), 256, 0, stream>>>(men1, vis1, mw2t, vw2t, MB2, VB2,
                                               menh, vish, 512, 0);
    attn_f18<<<dim3(9, 4, 32), 256, 0, stream>>>(menh, vish, aw1t, AB1, AW2, part);
    postproc<<<288, 256, 0, stream>>>(part, MM, CM, AB2, out);
}

// Round 31
// 75.925 us; speedup vs baseline: 2.4685x; 2.4685x over previous
//
#include <hip/hip_runtime.h>

typedef _Float16 f16;
typedef _Float16 f16x8 __attribute__((ext_vector_type(8)));
typedef _Float16 f16x4 __attribute__((ext_vector_type(4)));
typedef float f32x4 __attribute__((ext_vector_type(4)));
typedef float fl4 __attribute__((ext_vector_type(4)));

#define NEG_INF_F (-1e10f)

__device__ __forceinline__ void stage16(const f16* g, f16* l) {
    __builtin_amdgcn_global_load_lds((const __attribute__((address_space(1))) void*)g,
                                     (__attribute__((address_space(3))) void*)l, 16, 0, 0);
}

// ---------------- prep2: tiled transposes + conversions -------
__global__ __launch_bounds__(256) void prep2(const float* __restrict__ me,
                                             const float* __restrict__ mw1,
                                             const float* __restrict__ vw1,
                                             const float* __restrict__ mw2,
                                             const float* __restrict__ vw2,
                                             const float* __restrict__ aw1,
                                             const float* __restrict__ cl,
                                             f16* __restrict__ me_h,
                                             f16* __restrict__ mw1t, f16* __restrict__ vw1t,
                                             f16* __restrict__ mw2t, f16* __restrict__ vw2t,
                                             f16* __restrict__ aw1t, f16* __restrict__ cl_h) {
    int bx = blockIdx.x, t = threadIdx.x;
    if (bx < 1792) {
        __shared__ float tile[32][33];
        const float* src; f16* dst; int Ksrc, Kp, tid;
        if (bx < 512)       { src = mw1; dst = mw1t; Ksrc = 1024; Kp = 1024; tid = bx; }
        else if (bx < 1024) { src = vw1; dst = vw1t; Ksrc = 1000; Kp = 1024; tid = bx - 512; }
        else if (bx < 1280) { src = mw2; dst = mw2t; Ksrc = 512;  Kp = 512;  tid = bx - 1024; }
        else if (bx < 1536) { src = vw2; dst = vw2t; Ksrc = 512;  Kp = 512;  tid = bx - 1280; }
        else                { src = aw1; dst = aw1t; Ksrc = 512;  Kp = 512;  tid = bx - 1536; }
        int tk = tid >> 4, tn = tid & 15;
        int x = t & 31, y = t >> 5;
        #pragma unroll
        for (int r = 0; r < 4; r++) {
            int k = tk * 32 + y * 4 + r;
            tile[y * 4 + r][x] = (k < Ksrc) ? src[k * 512 + tn * 32 + x] : 0.f;
        }
        __syncthreads();
        #pragma unroll
        for (int r = 0; r < 4; r++) {
            int n = tn * 32 + y * 4 + r;
            dst[n * Kp + tk * 32 + x] = (f16)tile[x][y * 4 + r];
        }
        return;
    }
    if (bx < 3840) {
        int i = (bx - 1792) * 256 + t;
        fl4 v = *(const fl4*)(me + i * 4);
        f16x4 h;
        #pragma unroll
        for (int e = 0; e < 4; e++) h[e] = (f16)v[e];
        *(f16x4*)(me_h + i * 4) = h;
        return;
    }
    {
        int i = (bx - 3840) * 256 + t;
        int idx = i * 4;
        int r = idx >> 10, k0 = idx & 1023;
        f16x4 h;
        if (k0 < 1000) {
            fl4 v = *(const fl4*)(cl + r * 1000 + k0);
            #pragma unroll
            for (int e = 0; e < 4; e++) h[e] = (f16)v[e];
        } else {
            #pragma unroll
            for (int e = 0; e < 4; e++) h[e] = (f16)0.f;
        }
        *(f16x4*)(cl_h + idx) = h;
    }
}

// ---------------- staged GEMM, 64x64 tile, 4-buffer paired barriers ----------
__global__ __launch_bounds__(256, 4) void gemm_stg3(const f16* __restrict__ Am,
                                                    const f16* __restrict__ Av,
                                                    const f16* __restrict__ Wm,
                                                    const f16* __restrict__ Wv,
                                                    const float* __restrict__ bm,
                                                    const float* __restrict__ bv,
                                                    f16* __restrict__ om,
                                                    f16* __restrict__ ov,
                                                    int K, int relu) {
    __shared__ f16 ab[4][2048], bb[4][2048];  // 32KB

    int t = threadIdx.x, lane = t & 63, w = t >> 6;
    int rl = lane & 15, kg = lane >> 4;
    int mq = w & 1, nq = w >> 1;
    bool isv = blockIdx.x >= 32;
    int mb = isv ? blockIdx.x - 32 : blockIdx.x;
    const f16* A = isv ? Av : Am;
    const f16* Wt = isv ? Wv : Wm;
    const float* bias = isv ? bv : bm;
    f16* out = isv ? ov : om;
    int m0 = mb * 64, n0 = blockIdx.y * 64;
    int pu = kg ^ ((rl >> 1) & 3);

    int srow = t >> 2;
    int sk8 = (t & 3) ^ ((srow >> 1) & 3);
    const f16* a_src = A + (m0 + srow) * K + sk8 * 8;
    const f16* b_src = Wt + (n0 + srow) * K + sk8 * 8;
    int ndbl = K >> 6;   // double-steps (K/64)

    f32x4 acc[2][2] = {};

    stage16(a_src, &ab[0][t * 8]);
    stage16(b_src, &bb[0][t * 8]);
    stage16(a_src + 32, &ab[1][t * 8]);
    stage16(b_src + 32, &bb[1][t * 8]);
    __syncthreads();

    for (int ss = 0; ss < ndbl; ss++) {
        if (ss + 1 < ndbl) {
            int ka = (ss * 2 + 2) * 32, kb = (ss * 2 + 3) * 32;
            stage16(a_src + ka, &ab[(ss * 2 + 2) & 3][t * 8]);
            stage16(b_src + ka, &bb[(ss * 2 + 2) & 3][t * 8]);
            stage16(a_src + kb, &ab[(ss * 2 + 3) & 3][t * 8]);
            stage16(b_src + kb, &bb[(ss * 2 + 3) & 3][t * 8]);
        }
        #pragma unroll
        for (int h = 0; h < 2; h++) {
            int cur = (ss * 2 + h) & 3;
            f16x8 af[2], bf[2];
            #pragma unroll
            for (int f = 0; f < 2; f++) {
                af[f] = *(const f16x8*)&ab[cur][((mq * 32 + f * 16 + rl) * 4 + pu) * 8];
                bf[f] = *(const f16x8*)&bb[cur][((nq * 32 + f * 16 + rl) * 4 + pu) * 8];
            }
            #pragma unroll
            for (int fi = 0; fi < 2; fi++)
                #pragma unroll
                for (int fj = 0; fj < 2; fj++)
                    acc[fi][fj] = __builtin_amdgcn_mfma_f32_16x16x32_f16(af[fi], bf[fj], acc[fi][fj], 0, 0, 0);
        }
        __syncthreads();
    }

    #pragma unroll
    for (int fi = 0; fi < 2; fi++)
        #pragma unroll
        for (int fj = 0; fj < 2; fj++) {
            int col = n0 + nq * 32 + fj * 16 + rl;
            float bv2 = bias[col];
            #pragma unroll
            for (int r = 0; r < 4; r++) {
                int row = m0 + mq * 32 + fi * 16 + kg * 4 + r;
                float v = acc[fi][fj][r] + bv2;
                if (relu) v = fmaxf(v, 0.f);
                out[row * 512 + col] = (f16)v;
            }
        }
}

// ---------------- fused attention f14 (best measured): counted-vmcnt pipeline -------
// grid (9 cq, 4 jh, 32 b) = 1152 blocks, 256 thr (4 waves = 2mh x 2jq), bounds(256,2).
// acc[c4][fi2][fj4] = 128 VGPRs; 10 LDS reads -> 32 MFMAs per BK=32 step; 3-buffer
// counted-vmcnt schedule (batch s+2 issued post-barrier, uniform vmcnt(3)). LDS 42KB.
__global__ __launch_bounds__(256, 2) void attn_f14(const f16* __restrict__ men,
                                                   const f16* __restrict__ vis,
                                                   const f16* __restrict__ aw1t,
                                                   const float* __restrict__ ab1,
                                                   const float* __restrict__ aw2,
                                                   float* __restrict__ partial) {
    __shared__ f16 awb[3][4096];    // [buf][row j 0..127][unit 0..3][8 f16], swizzled
    __shared__ f16 mnb[3][2048];    // [buf][row m 0..63][unit][8], swizzled
    __shared__ f16 vist[2048];      // [c 0..3][k 0..511], staged once
    __shared__ float red[2][4][64]; // [jq][c][m]

    int t = threadIdx.x, lane = t & 63, w = t >> 6;
    int mh = w & 1, jq = w >> 1;
    int cq = blockIdx.x, jh = blockIdx.y, b = blockIdx.z;
    int c0 = cq * 4;
    int rl = lane & 15, kg = lane >> 4;
    int pu = kg ^ ((rl >> 1) & 3);

    int srow = t >> 2;                       // 0..63
    int sk8 = (t & 3) ^ ((srow >> 1) & 3);
    const f16* aw_src = aw1t + (jh * 128 + srow) * 512 + sk8 * 8;   // + i*64*512
    const f16* mn_src = men + (b * 64 + srow) * 512 + sk8 * 8;
    const f16* vi_src = vis + (b * 36 + c0 + (t >> 6)) * 512 + (t & 63) * 8;

    f32x4 acc[4][2][4] = {};   // [c][fi][fj]

    // prologue: vist + batches 0,1 (each batch: 2 aw + 1 mn per thread)
    stage16(vi_src, &vist[t * 8]);
    stage16(aw_src, &awb[0][t * 8]);
    stage16(aw_src + 64 * 512, &awb[0][2048 + t * 8]);
    stage16(mn_src, &mnb[0][t * 8]);
    stage16(aw_src + 32, &awb[1][t * 8]);
    stage16(aw_src + 64 * 512 + 32, &awb[1][2048 + t * 8]);
    stage16(mn_src + 32, &mnb[1][t * 8]);
    asm volatile("s_waitcnt vmcnt(3)" ::: "memory");   // retire vist + batch0
    __builtin_amdgcn_s_barrier();
    __builtin_amdgcn_sched_barrier(0);

    #pragma unroll
    for (int s = 0; s < 16; s++) {
        if (s > 0) {
            if (s == 15) asm volatile("s_waitcnt vmcnt(0)" ::: "memory");
            else         asm volatile("s_waitcnt vmcnt(3)" ::: "memory");
            __builtin_amdgcn_s_barrier();
            __builtin_amdgcn_sched_barrier(0);
        }
        if (s <= 13) {  // issue batch s+2 EARLY (lands during steps s, s+1)
            int k2 = (s + 2) * 32;
            int nb = (s + 2) % 3;
            stage16(aw_src + k2, &awb[nb][t * 8]);
            stage16(aw_src + 64 * 512 + k2, &awb[nb][2048 + t * 8]);
            stage16(mn_src + k2, &mnb[nb][t * 8]);
        }

        const int cur = s % 3;
        f16x8 mm[2], bf[4], vv[4];
        #pragma unroll
        for (int fi = 0; fi < 2; fi++)
            mm[fi] = *(const f16x8*)&mnb[cur][((mh * 32 + fi * 16 + rl) * 4 + pu) * 8];
        #pragma unroll
        for (int fj = 0; fj < 4; fj++)
            bf[fj] = *(const f16x8*)&awb[cur][((jq * 64 + fj * 16 + rl) * 4 + pu) * 8];
        #pragma unroll
        for (int c = 0; c < 4; c++)
            vv[c] = *(const f16x8*)&vist[c * 512 + s * 32 + kg * 8];  // broadcast

        #pragma unroll
        for (int fi = 0; fi < 2; fi++)
            #pragma unroll
            for (int c = 0; c < 4; c++) {
                f16x8 a = mm[fi] * vv[c];   // 4 pk_mul -> feeds 4 MFMAs
                #pragma unroll
                for (int fj = 0; fj < 4; fj++)
                    acc[c][fi][fj] = __builtin_amdgcn_mfma_f32_16x16x32_f16(a, bf[fj], acc[c][fi][fj], 0, 0, 0);
            }
    }

    // fold: part[m] = sum over this wave's 64 j of relu(acc + ab1) * aw2 (fp32)
    int j0 = jh * 128 + jq * 64;
    float ab1v[4], aw2v[4];
    #pragma unroll
    for (int fj = 0; fj < 4; fj++) {
        int j = j0 + fj * 16 + rl;
        ab1v[fj] = ab1[j];
        aw2v[fj] = aw2[j];
    }
    #pragma unroll
    for (int c = 0; c < 4; c++) {
        float part[2][4];
        #pragma unroll
        for (int fi = 0; fi < 2; fi++)
            #pragma unroll
            for (int r = 0; r < 4; r++) {
                float sv = 0.f;
                #pragma unroll
                for (int fj = 0; fj < 4; fj++)
                    sv += fmaxf(acc[c][fi][fj][r] + ab1v[fj], 0.f) * aw2v[fj];
                part[fi][r] = sv;
            }
        #pragma unroll
        for (int mask = 1; mask < 16; mask <<= 1)
            #pragma unroll
            for (int fi = 0; fi < 2; fi++)
                #pragma unroll
                for (int r = 0; r < 4; r++)
                    part[fi][r] += __shfl_xor(part[fi][r], mask);
        float myv = 0.f;
        #pragma unroll
        for (int fi = 0; fi < 2; fi++)
            #pragma unroll
            for (int r = 0; r < 4; r++)
                myv = (rl == fi * 4 + r) ? part[fi][r] : myv;
        if (rl < 8) {
            int m = mh * 32 + (rl >> 2) * 16 + kg * 4 + (rl & 3);
            red[jq][c][m] = myv;
        }
    }
    __syncthreads();

    if (t < 256) {
        int ci = t >> 6, m = t & 63;
        float s = red[0][ci][m] + red[1][ci][m];
        partial[((jh * 32 + b) * 64 + m) * 36 + c0 + ci] = s;
    }
}

// ---------------- post-process: sum 4 jh partials, + ab2, masks, NEG_INF ------------
__global__ __launch_bounds__(256) void postproc(const float* __restrict__ partial,
                                                const float* __restrict__ mm,
                                                const float* __restrict__ cm,
                                                const float* __restrict__ ab2,
                                                float* __restrict__ out) {
    int i = blockIdx.x * 256 + threadIdx.x;  // < 73728
    int b = i / 2304;
    int rest = i - b * 2304;
    int m = rest / 36, c = rest - m * 36;
    float s = 0.f;
    #pragma unroll
    for (int jh = 0; jh < 4; jh++)
        s += partial[((jh * 32 + b) * 64 + m) * 36 + c];
    float v = (s + ab2[0]) * mm[b * 64 + m] * cm[b * 36 + c];
    out[i] = (v != 0.f) ? v : NEG_INF_F;
}

extern "C" void kernel_launch(void* const* d_in, const int* in_sizes, int n_in,
                              void* d_out, int out_size, void* d_ws, size_t ws_size,
                              hipStream_t stream) {
    const float* ME  = (const float*)d_in[0];   // (32,64,1024)
    const float* CL  = (const float*)d_in[1];   // (32,36,1000)
    const float* MM  = (const float*)d_in[2];   // (32,64)
    const float* CM  = (const float*)d_in[3];   // (32,36)
    const float* VW1 = (const float*)d_in[4];   // (1000,512)
    const float* VB1 = (const float*)d_in[5];
    const float* VW2 = (const float*)d_in[6];   // (512,512)
    const float* VB2 = (const float*)d_in[7];
    const float* MW1 = (const float*)d_in[8];   // (1024,512)
    const float* MB1 = (const float*)d_in[9];
    const float* MW2 = (const float*)d_in[10];  // (512,512)
    const float* MB2 = (const float*)d_in[11];
    const float* AW1 = (const float*)d_in[12];  // (512,512)
    const float* AB1 = (const float*)d_in[13];
    const float* AW2 = (const float*)d_in[14];  // (512,1)
    const float* AB2 = (const float*)d_in[15];  // (1,)
    float* out = (float*)d_out;

    char* ws = (char*)d_ws;
    f16* me_h  = (f16*)ws; ws += (size_t)2048 * 1024 * 2;
    f16* cl_h  = (f16*)ws; ws += (size_t)1152 * 1024 * 2;
    f16* mw1t  = (f16*)ws; ws += (size_t)512 * 1024 * 2;
    f16* vw1t  = (f16*)ws; ws += (size_t)512 * 1024 * 2;
    f16* mw2t  = (f16*)ws; ws += (size_t)512 * 512 * 2;
    f16* vw2t  = (f16*)ws; ws += (size_t)512 * 512 * 2;
    f16* aw1t  = (f16*)ws; ws += (size_t)512 * 512 * 2;
    f16* men1  = (f16*)ws; ws += (size_t)2048 * 512 * 2;
    f16* menh  = (f16*)ws; ws += (size_t)2048 * 512 * 2;
    f16* vis1  = (f16*)ws; ws += (size_t)1152 * 512 * 2;
    f16* vish  = (f16*)ws; ws += (size_t)1152 * 512 * 2;
    float* part = (float*)ws; ws += (size_t)4 * 32 * 64 * 36 * 4;

    prep2<<<4992, 256, 0, stream>>>(ME, MW1, VW1, MW2, VW2, AW1, CL,
                                    me_h, mw1t, vw1t, mw2t, vw2t, aw1t, cl_h);
    gemm_stg3<<<dim3(50, 8), 256, 0, stream>>>(me_h, cl_h, mw1t, vw1t, MB1, VB1,
                                               men1, vis1, 1024, 1);
    gemm_stg3<<<dim3(50, 8), 256, 0, stream>>>(men1, vis1, mw2t, vw2t, MB2, VB2,
                                               menh, vish, 512, 0);
    attn_f14<<<dim3(9, 4, 32), 256, 0, stream>>>(menh, vish, aw1t, AB1, AW2, part);
    postproc<<<288, 256, 0, stream>>>(part, MM, CM, AB2, out);
}

// Round 32
// 74.103 us; speedup vs baseline: 2.5292x; 1.0246x over previous
//
#include <hip/hip_runtime.h>

typedef _Float16 f16;
typedef _Float16 f16x8 __attribute__((ext_vector_type(8)));
typedef _Float16 f16x4 __attribute__((ext_vector_type(4)));
typedef float f32x4 __attribute__((ext_vector_type(4)));
typedef float fl4 __attribute__((ext_vector_type(4)));

#define NEG_INF_F (-1e10f)

__device__ __forceinline__ void stage16(const f16* g, f16* l) {
    __builtin_amdgcn_global_load_lds((const __attribute__((address_space(1))) void*)g,
                                     (__attribute__((address_space(3))) void*)l, 16, 0, 0);
}

// ---------------- prep2: tiled transposes + conversions (unchanged) -------
__global__ __launch_bounds__(256) void prep2(const float* __restrict__ me,
                                             const float* __restrict__ mw1,
                                             const float* __restrict__ vw1,
                                             const float* __restrict__ mw2,
                                             const float* __restrict__ vw2,
                                             const float* __restrict__ aw1,
                                             const float* __restrict__ cl,
                                             f16* __restrict__ me_h,
                                             f16* __restrict__ mw1t, f16* __restrict__ vw1t,
                                             f16* __restrict__ mw2t, f16* __restrict__ vw2t,
                                             f16* __restrict__ aw1t, f16* __restrict__ cl_h) {
    int bx = blockIdx.x, t = threadIdx.x;
    if (bx < 1792) {
        __shared__ float tile[32][33];
        const float* src; f16* dst; int Ksrc, Kp, tid;
        if (bx < 512)       { src = mw1; dst = mw1t; Ksrc = 1024; Kp = 1024; tid = bx; }
        else if (bx < 1024) { src = vw1; dst = vw1t; Ksrc = 1000; Kp = 1024; tid = bx - 512; }
        else if (bx < 1280) { src = mw2; dst = mw2t; Ksrc = 512;  Kp = 512;  tid = bx - 1024; }
        else if (bx < 1536) { src = vw2; dst = vw2t; Ksrc = 512;  Kp = 512;  tid = bx - 1280; }
        else                { src = aw1; dst = aw1t; Ksrc = 512;  Kp = 512;  tid = bx - 1536; }
        int tk = tid >> 4, tn = tid & 15;
        int x = t & 31, y = t >> 5;
        #pragma unroll
        for (int r = 0; r < 4; r++) {
            int k = tk * 32 + y * 4 + r;
            tile[y * 4 + r][x] = (k < Ksrc) ? src[k * 512 + tn * 32 + x] : 0.f;
        }
        __syncthreads();
        #pragma unroll
        for (int r = 0; r < 4; r++) {
            int n = tn * 32 + y * 4 + r;
            dst[n * Kp + tk * 32 + x] = (f16)tile[x][y * 4 + r];
        }
        return;
    }
    if (bx < 3840) {
        int i = (bx - 1792) * 256 + t;
        fl4 v = *(const fl4*)(me + i * 4);
        f16x4 h;
        #pragma unroll
        for (int e = 0; e < 4; e++) h[e] = (f16)v[e];
        *(f16x4*)(me_h + i * 4) = h;
        return;
    }
    {
        int i = (bx - 3840) * 256 + t;
        int idx = i * 4;
        int r = idx >> 10, k0 = idx & 1023;
        f16x4 h;
        if (k0 < 1000) {
            fl4 v = *(const fl4*)(cl + r * 1000 + k0);
            #pragma unroll
            for (int e = 0; e < 4; e++) h[e] = (f16)v[e];
        } else {
            #pragma unroll
            for (int e = 0; e < 4; e++) h[e] = (f16)0.f;
        }
        *(f16x4*)(cl_h + idx) = h;
    }
}

// ---------------- staged GEMM, 64x64 tile, 4-buffer paired barriers (unchanged) ------
__global__ __launch_bounds__(256, 4) void gemm_stg3(const f16* __restrict__ Am,
                                                    const f16* __restrict__ Av,
                                                    const f16* __restrict__ Wm,
                                                    const f16* __restrict__ Wv,
                                                    const float* __restrict__ bm,
                                                    const float* __restrict__ bv,
                                                    f16* __restrict__ om,
                                                    f16* __restrict__ ov,
                                                    int K, int relu) {
    __shared__ f16 ab[4][2048], bb[4][2048];  // 32KB

    int t = threadIdx.x, lane = t & 63, w = t >> 6;
    int rl = lane & 15, kg = lane >> 4;
    int mq = w & 1, nq = w >> 1;
    bool isv = blockIdx.x >= 32;
    int mb = isv ? blockIdx.x - 32 : blockIdx.x;
    const f16* A = isv ? Av : Am;
    const f16* Wt = isv ? Wv : Wm;
    const float* bias = isv ? bv : bm;
    f16* out = isv ? ov : om;
    int m0 = mb * 64, n0 = blockIdx.y * 64;
    int pu = kg ^ ((rl >> 1) & 3);

    int srow = t >> 2;
    int sk8 = (t & 3) ^ ((srow >> 1) & 3);
    const f16* a_src = A + (m0 + srow) * K + sk8 * 8;
    const f16* b_src = Wt + (n0 + srow) * K + sk8 * 8;
    int ndbl = K >> 6;   // double-steps (K/64)

    f32x4 acc[2][2] = {};

    stage16(a_src, &ab[0][t * 8]);
    stage16(b_src, &bb[0][t * 8]);
    stage16(a_src + 32, &ab[1][t * 8]);
    stage16(b_src + 32, &bb[1][t * 8]);
    __syncthreads();

    for (int ss = 0; ss < ndbl; ss++) {
        if (ss + 1 < ndbl) {
            int ka = (ss * 2 + 2) * 32, kb = (ss * 2 + 3) * 32;
            stage16(a_src + ka, &ab[(ss * 2 + 2) & 3][t * 8]);
            stage16(b_src + ka, &bb[(ss * 2 + 2) & 3][t * 8]);
            stage16(a_src + kb, &ab[(ss * 2 + 3) & 3][t * 8]);
            stage16(b_src + kb, &bb[(ss * 2 + 3) & 3][t * 8]);
        }
        #pragma unroll
        for (int h = 0; h < 2; h++) {
            int cur = (ss * 2 + h) & 3;
            f16x8 af[2], bf[2];
            #pragma unroll
            for (int f = 0; f < 2; f++) {
                af[f] = *(const f16x8*)&ab[cur][((mq * 32 + f * 16 + rl) * 4 + pu) * 8];
                bf[f] = *(const f16x8*)&bb[cur][((nq * 32 + f * 16 + rl) * 4 + pu) * 8];
            }
            #pragma unroll
            for (int fi = 0; fi < 2; fi++)
                #pragma unroll
                for (int fj = 0; fj < 2; fj++)
                    acc[fi][fj] = __builtin_amdgcn_mfma_f32_16x16x32_f16(af[fi], bf[fj], acc[fi][fj], 0, 0, 0);
        }
        __syncthreads();
    }

    #pragma unroll
    for (int fi = 0; fi < 2; fi++)
        #pragma unroll
        for (int fj = 0; fj < 2; fj++) {
            int col = n0 + nq * 32 + fj * 16 + rl;
            float bv2 = bias[col];
            #pragma unroll
            for (int r = 0; r < 4; r++) {
                int row = m0 + mq * 32 + fi * 16 + kg * 4 + r;
                float v = acc[fi][fj][r] + bv2;
                if (relu) v = fmaxf(v, 0.f);
                out[row * 512 + col] = (f16)v;
            }
        }
}

// ---------------- fused attention f19: f14 + cross-step LDS->reg pre-read ----------
// grid (9 cq, 4 jh, 32 b), 256 thr (4 waves = 2mh x 2jq), bounds(256,2). 4 LDS buffers
// (54KB), staging 3-ahead, invariant "only newest batch outstanding" (vmcnt(3)) so
// buffer s+1 is valid DURING step s. Loop: {wait,barrier} -> issue batch s+3 -> MFMA
// step s from PRE-READ regs (zero lgkm dependency at barrier exit -> matrix pipe fed
// immediately) -> ds_read step s+1 frags -> sched_barrier(0). Full unroll = static idx.
__global__ __launch_bounds__(256, 2) void attn_f19(const f16* __restrict__ men,
                                                   const f16* __restrict__ vis,
                                                   const f16* __restrict__ aw1t,
                                                   const float* __restrict__ ab1,
                                                   const float* __restrict__ aw2,
                                                   float* __restrict__ partial) {
    __shared__ f16 awb[4][4096];    // [buf][row j 0..127][unit 0..3][8 f16], swizzled
    __shared__ f16 mnb[4][2048];    // [buf][row m 0..63][unit][8], swizzled
    __shared__ f16 vist[2048];      // [c 0..3][k 0..511], staged once
    __shared__ float red[2][4][64]; // [jq][c][m]

    int t = threadIdx.x, lane = t & 63, w = t >> 6;
    int mh = w & 1, jq = w >> 1;
    int cq = blockIdx.x, jh = blockIdx.y, b = blockIdx.z;
    int c0 = cq * 4;
    int rl = lane & 15, kg = lane >> 4;
    int pu = kg ^ ((rl >> 1) & 3);

    int srow = t >> 2;                       // 0..63
    int sk8 = (t & 3) ^ ((srow >> 1) & 3);
    const f16* aw_src = aw1t + (jh * 128 + srow) * 512 + sk8 * 8;   // + i*64*512
    const f16* mn_src = men + (b * 64 + srow) * 512 + sk8 * 8;
    const f16* vi_src = vis + (b * 36 + c0 + (t >> 6)) * 512 + (t & 63) * 8;

    f32x4 acc[4][2][4] = {};   // [c][fi][fj]

    // prologue: vist + batches 0,1,2 (each batch: 2 aw + 1 mn per thread)
    stage16(vi_src, &vist[t * 8]);
    #pragma unroll
    for (int bt = 0; bt < 3; bt++) {
        stage16(aw_src + bt * 32, &awb[bt][t * 8]);
        stage16(aw_src + 64 * 512 + bt * 32, &awb[bt][2048 + t * 8]);
        stage16(mn_src + bt * 32, &mnb[bt][t * 8]);
    }
    // retire vist + batches 0,1 (only newest batch 2 outstanding = 3 ops)
    asm volatile("s_waitcnt vmcnt(3)" ::: "memory");
    __builtin_amdgcn_s_barrier();
    __builtin_amdgcn_sched_barrier(0);

    // pre-read step 0 fragments
    f16x8 cmm[2], cbf[4], cvv[4];
    #pragma unroll
    for (int fi = 0; fi < 2; fi++)
        cmm[fi] = *(const f16x8*)&mnb[0][((mh * 32 + fi * 16 + rl) * 4 + pu) * 8];
    #pragma unroll
    for (int fj = 0; fj < 4; fj++)
        cbf[fj] = *(const f16x8*)&awb[0][((jq * 64 + fj * 16 + rl) * 4 + pu) * 8];
    #pragma unroll
    for (int c = 0; c < 4; c++)
        cvv[c] = *(const f16x8*)&vist[c * 512 + kg * 8];
    __builtin_amdgcn_sched_barrier(0);

    #pragma unroll
    for (int s = 0; s < 16; s++) {
        if (s > 0) {
            if (s >= 14) asm volatile("s_waitcnt vmcnt(0)" ::: "memory");
            else         asm volatile("s_waitcnt vmcnt(3)" ::: "memory");
            __builtin_amdgcn_s_barrier();
            __builtin_amdgcn_sched_barrier(0);
        }
        if (s <= 12) {  // issue batch s+3 (lands during steps s..s+2)
            int k3 = (s + 3) * 32;
            int nb = (s + 3) & 3;
            stage16(aw_src + k3, &awb[nb][t * 8]);
            stage16(aw_src + 64 * 512 + k3, &awb[nb][2048 + t * 8]);
            stage16(mn_src + k3, &mnb[nb][t * 8]);
        }

        // MFMA step s from PRE-READ registers (no lgkm dependency here)
        #pragma unroll
        for (int fi = 0; fi < 2; fi++)
            #pragma unroll
            for (int c = 0; c < 4; c++) {
                f16x8 a = cmm[fi] * cvv[c];   // 4 pk_mul -> feeds 4 MFMAs
                #pragma unroll
                for (int fj = 0; fj < 4; fj++)
                    acc[c][fi][fj] = __builtin_amdgcn_mfma_f32_16x16x32_f16(a, cbf[fj], acc[c][fi][fj], 0, 0, 0);
            }

        if (s < 15) {  // pre-read step s+1 (buffer (s+1)&3 valid: batch s+1 retired)
            const int nx = (s + 1) & 3;
            f16x8 nmm[2], nbf[4], nvv[4];
            #pragma unroll
            for (int fi = 0; fi < 2; fi++)
                nmm[fi] = *(const f16x8*)&mnb[nx][((mh * 32 + fi * 16 + rl) * 4 + pu) * 8];
            #pragma unroll
            for (int fj = 0; fj < 4; fj++)
                nbf[fj] = *(const f16x8*)&awb[nx][((jq * 64 + fj * 16 + rl) * 4 + pu) * 8];
            #pragma unroll
            for (int c = 0; c < 4; c++)
                nvv[c] = *(const f16x8*)&vist[c * 512 + (s + 1) * 32 + kg * 8];
            __builtin_amdgcn_sched_barrier(0);
            #pragma unroll
            for (int fi = 0; fi < 2; fi++) cmm[fi] = nmm[fi];
            #pragma unroll
            for (int fj = 0; fj < 4; fj++) cbf[fj] = nbf[fj];
            #pragma unroll
            for (int c = 0; c < 4; c++) cvv[c] = nvv[c];
        }
    }

    // fold: part[m] = sum over this wave's 64 j of relu(acc + ab1) * aw2 (fp32)
    int j0 = jh * 128 + jq * 64;
    float ab1v[4], aw2v[4];
    #pragma unroll
    for (int fj = 0; fj < 4; fj++) {
        int j = j0 + fj * 16 + rl;
        ab1v[fj] = ab1[j];
        aw2v[fj] = aw2[j];
    }
    #pragma unroll
    for (int c = 0; c < 4; c++) {
        float part[2][4];
        #pragma unroll
        for (int fi = 0; fi < 2; fi++)
            #pragma unroll
            for (int r = 0; r < 4; r++) {
                float sv = 0.f;
                #pragma unroll
                for (int fj = 0; fj < 4; fj++)
                    sv += fmaxf(acc[c][fi][fj][r] + ab1v[fj], 0.f) * aw2v[fj];
                part[fi][r] = sv;
            }
        #pragma unroll
        for (int mask = 1; mask < 16; mask <<= 1)
            #pragma unroll
            for (int fi = 0; fi < 2; fi++)
                #pragma unroll
                for (int r = 0; r < 4; r++)
                    part[fi][r] += __shfl_xor(part[fi][r], mask);
        float myv = 0.f;
        #pragma unroll
        for (int fi = 0; fi < 2; fi++)
            #pragma unroll
            for (int r = 0; r < 4; r++)
                myv = (rl == fi * 4 + r) ? part[fi][r] : myv;
        if (rl < 8) {
            int m = mh * 32 + (rl >> 2) * 16 + kg * 4 + (rl & 3);
            red[jq][c][m] = myv;
        }
    }
    __syncthreads();

    if (t < 256) {
        int ci = t >> 6, m = t & 63;
        float s = red[0][ci][m] + red[1][ci][m];
        partial[((jh * 32 + b) * 64 + m) * 36 + c0 + ci] = s;
    }
}

// ---------------- post-process: sum 4 jh partials, + ab2, masks, NEG_INF ------------
__global__ __launch_bounds__(256) void postproc(const float* __restrict__ partial,
                                                const float* __restrict__ mm,
                                                const float* __restrict__ cm,
                                                const float* __restrict__ ab2,
                                                float* __restrict__ out) {
    int i = blockIdx.x * 256 + threadIdx.x;  // < 73728
    int b = i / 2304;
    int rest = i - b * 2304;
    int m = rest / 36, c = rest - m * 36;
    float s = 0.f;
    #pragma unroll
    for (int jh = 0; jh < 4; jh++)
        s += partial[((jh * 32 + b) * 64 + m) * 36 + c];
    float v = (s + ab2[0]) * mm[b * 64 + m] * cm[b * 36 + c];
    out[i] = (v != 0.f) ? v : NEG_INF_F;
}

extern "C" void kernel_launch(void* const* d_in, const int* in_sizes, int n_in,
                              void* d_out, int out_size, void* d_ws, size_t ws_size,
                              hipStream_t stream) {
    const float* ME  = (const float*)d_in[0];   // (32,64,1024)
    const float* CL  = (const float*)d_in[1];   // (32,36,1000)
    const float* MM  = (const float*)d_in[2];   // (32,64)
    const float* CM  = (const float*)d_in[3];   // (32,36)
    const float* VW1 = (const float*)d_in[4];   // (1000,512)
    const float* VB1 = (const float*)d_in[5];
    const float* VW2 = (const float*)d_in[6];   // (512,512)
    const float* VB2 = (const float*)d_in[7];
    const float* MW1 = (const float*)d_in[8];   // (1024,512)
    const float* MB1 = (const float*)d_in[9];
    const float* MW2 = (const float*)d_in[10];  // (512,512)
    const float* MB2 = (const float*)d_in[11];
    const float* AW1 = (const float*)d_in[12];  // (512,512)
    const float* AB1 = (const float*)d_in[13];
    const float* AW2 = (const float*)d_in[14];  // (512,1)
    const float* AB2 = (const float*)d_in[15];  // (1,)
    float* out = (float*)d_out;

    char* ws = (char*)d_ws;
    f16* me_h  = (f16*)ws; ws += (size_t)2048 * 1024 * 2;
    f16* cl_h  = (f16*)ws; ws += (size_t)1152 * 1024 * 2;
    f16* mw1t  = (f16*)ws; ws += (size_t)512 * 1024 * 2;
    f16* vw1t  = (f16*)ws; ws += (size_t)512 * 1024 * 2;
    f16* mw2t  = (f16*)ws; ws += (size_t)512 * 512 * 2;
    f16* vw2t  = (f16*)ws; ws += (size_t)512 * 512 * 2;
    f16* aw1t  = (f16*)ws; ws += (size_t)512 * 512 * 2;
    f16* men1  = (f16*)ws; ws += (size_t)2048 * 512 * 2;
    f16* menh  = (f16*)ws; ws += (size_t)2048 * 512 * 2;
    f16* vis1  = (f16*)ws; ws += (size_t)1152 * 512 * 2;
    f16* vish  = (f16*)ws; ws += (size_t)1152 * 512 * 2;
    float* part = (float*)ws; ws += (size_t)4 * 32 * 64 * 36 * 4;

    prep2<<<4992, 256, 0, stream>>>(ME, MW1, VW1, MW2, VW2, AW1, CL,
                                    me_h, mw1t, vw1t, mw2t, vw2t, aw1t, cl_h);
    gemm_stg3<<<dim3(50, 8), 256, 0, stream>>>(me_h, cl_h, mw1t, vw1t, MB1, VB1,
                                               men1, vis1, 1024, 1);
    gemm_stg3<<<dim3(50, 8), 256, 0, stream>>>(men1, vis1, mw2t, vw2t, MB2, VB2,
                                               menh, vish, 512, 0);
    attn_f19<<<dim3(9, 4, 32), 256, 0, stream>>>(menh, vish, aw1t, AB1, AW2, part);
    postproc<<<288, 256, 0, stream>>>(part, MM, CM, AB2, out);
}